// Round 6
// baseline (19.535 us; speedup 1.0000x reference)
//
#include <hip/hip_runtime.h>
#include <hip/hip_bf16.h>

// FrameReducer: N=16, T=2048, C=512, V=500 — two dispatches, no idx array.
//
// Kernel 1 (mask): N*T/256 blocks x 256 thr (full chip). Per wave:
//   keep[t] = (ctc[n,t,blank] < log(0.9)) && (t < x_lens[n]); __ballot ->
//   masks[chunk] (u64) + counts[chunk] (popcount), chunk = (n*T+t)>>6.
// Kernel 2 (gather): grid (ceil(Tp/16), N), 256 thr, 16 rows/block.
//   Once per block: lanes 0..31 wave-scan counts[n][*] -> LDS prefix[33]
//   (fixes R2's serial per-row scan). Per row p: binary search chunk,
//   k-th-set-bit select in the u64 mask -> tsrc; copy row 32B/lane.
//   p >= lens rows write zeros (harness never re-poisons d_out).
//   Block (0,n) writes lens_out[n] float tail.

__global__ void mask_kernel(const float* __restrict__ ctc,
                            const void* __restrict__ x_lens_raw,
                            const int* __restrict__ blank_id_p,
                            int N, int T, int V,
                            unsigned long long* __restrict__ masks,
                            int* __restrict__ counts) {
    const int gidx = blockIdx.x * blockDim.x + threadIdx.x;   // < N*T
    const int lane = threadIdx.x & 63;
    const int NT = N * T;

    bool keep = false;
    if (gidx < NT) {
        int n = gidx / T;
        int t = gidx - n * T;
        // x_lens dtype detection: values in [1,T], never 0 -> int64 layout
        // iff int32 view at odd index is 0.
        const int* li = (const int*)x_lens_raw;
        long long L = (N > 1 && li[1] == 0) ? ((const long long*)x_lens_raw)[n]
                                            : (long long)li[n];
        float v = ctc[(long long)gidx * V + *blank_id_p];
        keep = (v < -0.10536052f) && ((long long)t < L);      // float32(log(0.9))
    }
    unsigned long long bal = __ballot(keep);
    if (lane == 0 && gidx < NT) {
        masks[gidx >> 6] = bal;
        counts[gidx >> 6] = __popcll(bal);
    }
}

#define RPB 16   // rows per gather block

__global__ __launch_bounds__(256) void gather_kernel(
        const float* __restrict__ x,
        const unsigned long long* __restrict__ masks,
        const int* __restrict__ counts,
        float* __restrict__ out,
        float* __restrict__ lens_out,
        int Tp, int T) {
    const int C = 512;
    const int NCPS = T >> 6;                     // 32 chunks per sequence
    const int n    = blockIdx.y;
    const int tid  = threadIdx.x;
    const int lane = tid & 63;
    const int sub  = tid >> 6;                   // wave id = row-within-pass

    __shared__ int pfx[65];                      // exclusive prefix, pfx[NCPS]=lens

    if (tid < 64) {
        int c = tid;
        int v = (c < NCPS) ? counts[n * NCPS + c] : 0;
        int incl = v;
        #pragma unroll
        for (int d = 1; d < 64; d <<= 1) {
            int o = __shfl_up(incl, d, 64);
            if (lane >= d) incl += o;
        }
        if (c < NCPS) pfx[c + 1] = incl;
        if (c == 0) pfx[0] = 0;
    }
    __syncthreads();
    const int lens = pfx[NCPS];
    if (blockIdx.x == 0 && tid == 0) lens_out[n] = (float)lens;

    for (int pass = 0; pass < RPB / 4; ++pass) {
        int p = blockIdx.x * RPB + pass * 4 + sub;   // wave-uniform
        if (p >= Tp) break;

        float4 a = make_float4(0.f, 0.f, 0.f, 0.f);
        float4 b = a;
        if (p < lens) {
            int lo = 0, hi = NCPS;                   // largest c: pfx[c] <= p
            while (hi - lo > 1) {
                int mid = (lo + hi) >> 1;
                if (pfx[mid] <= p) lo = mid; else hi = mid;
            }
            int r = p - pfx[lo];
            unsigned long long m = masks[n * NCPS + lo];
            int base = 0;
            #pragma unroll
            for (int w = 32; w >= 1; w >>= 1) {
                int cnt = __popcll(m & ((1ull << w) - 1ull));
                if (r >= cnt) { r -= cnt; m >>= w; base += w; }
            }
            int tsrc = (lo << 6) + base;
            const float4* src = (const float4*)(x + ((long long)n * T + tsrc) * C);
            a = src[lane * 2];
            b = src[lane * 2 + 1];
        }
        float4* dst = (float4*)(out + ((long long)n * Tp + p) * C);
        dst[lane * 2]     = a;
        dst[lane * 2 + 1] = b;
    }
}

extern "C" void kernel_launch(void* const* d_in, const int* in_sizes, int n_in,
                              void* d_out, int out_size, void* d_ws, size_t ws_size,
                              hipStream_t stream) {
    const float* x        = (const float*)d_in[0];
    const void*  x_lens   = d_in[1];
    const float* ctc      = (const float*)d_in[2];
    const int*   blank_id = (const int*)d_in[3];

    const int N = in_sizes[1];               // 16
    const int C = 512;
    const int V = 500;
    const int T = in_sizes[0] / (N * C);     // 2048
    const int Tp = (out_size - N) / (N * C); // T'
    const int NCPS = T >> 6;                 // 32

    unsigned long long* masks = (unsigned long long*)d_ws;   // [N*NCPS]
    int* counts = (int*)(masks + (long long)N * NCPS);       // [N*NCPS]

    float* out      = (float*)d_out;                         // [N][Tp][C]
    float* lens_out = out + (long long)N * Tp * C;           // [N] float

    const int NT = N * T;
    mask_kernel<<<(NT + 255) / 256, 256, 0, stream>>>(ctc, x_lens, blank_id,
                                                      N, T, V, masks, counts);

    dim3 ggrid((Tp + RPB - 1) / RPB, N);
    gather_kernel<<<ggrid, 256, 0, stream>>>(x, masks, counts, out, lens_out, Tp, T);
}